// Round 1
// baseline (301.577 us; speedup 1.0000x reference)
//
#include <hip/hip_runtime.h>
#include <stdint.h>
#include <type_traits>

typedef unsigned short u16;
typedef __attribute__((ext_vector_type(8))) short bf16x8;
typedef __attribute__((ext_vector_type(4))) float f32x4;
typedef __attribute__((ext_vector_type(4))) int   i32x4;

#define TSEQ   2048
#define DMODEL 1024
#define NHEAD  16
#define DHEAD  64

__device__ __forceinline__ u16 f2bf(float f) {
  union { float f; uint32_t u; } v; v.f = f;
  uint32_t r = v.u + 0x7FFFu + ((v.u >> 16) & 1u);  // RNE
  return (u16)(r >> 16);
}

// ---------------- f32 -> bf16 conversion ----------------
__global__ void cvt_f32_bf16(const float* __restrict__ src, u16* __restrict__ dst, int n4) {
  int i = blockIdx.x * blockDim.x + threadIdx.x;
  if (i >= n4) return;
  float4 f = ((const float4*)src)[i];
  ushort4 o;
  o.x = f2bf(f.x); o.y = f2bf(f.y); o.z = f2bf(f.z); o.w = f2bf(f.w);
  ((ushort4*)dst)[i] = o;
}

// ---------------- GEMM: C[M,N] = A[M,K] @ W[N,K]^T  (both K-contiguous) ----------------
// 128x128 tile, BK=64, 4 waves (2x2), 16x16x32 bf16 MFMA.
// blockIdx.z picks among up to 3 (A,W,C) triples (fused QKV).
template <typename OUT_T>
__global__ __launch_bounds__(256, 2)
void gemm_bt(const u16* A0, const u16* W0, OUT_T* C0,
             const u16* A1, const u16* W1, OUT_T* C1,
             const u16* A2, const u16* W2, OUT_T* C2,
             int M, int N, int K) {
  const u16* A = A0; const u16* W = W0; OUT_T* C = C0;
  if (blockIdx.z == 1) { A = A1; W = W1; C = C1; }
  if (blockIdx.z == 2) { A = A2; W = W2; C = C2; }

  __shared__ u16 lA[128 * 72];
  __shared__ u16 lB[128 * 72];

  const int tid  = threadIdx.x;
  const int lane = tid & 63;
  const int wid  = tid >> 6;
  const int wr = wid >> 1, wc = wid & 1;
  const int g = lane >> 4, l15 = lane & 15;
  const int row0 = blockIdx.y * 128;
  const int col0 = blockIdx.x * 128;
  const int srow = tid >> 3;          // 0..31
  const int scol = (tid & 7) * 8;     // 0..56

  const f32x4 vzero = {0.f, 0.f, 0.f, 0.f};
  f32x4 acc[4][4];
#pragma unroll
  for (int m = 0; m < 4; ++m)
#pragma unroll
    for (int n = 0; n < 4; ++n) acc[m][n] = vzero;

  for (int k0 = 0; k0 < K; k0 += 64) {
    __syncthreads();
#pragma unroll
    for (int c = 0; c < 4; ++c) {
      int r = srow + c * 32;
      *(i32x4*)&lA[r * 72 + scol] = *(const i32x4*)&A[(size_t)(row0 + r) * K + k0 + scol];
      *(i32x4*)&lB[r * 72 + scol] = *(const i32x4*)&W[(size_t)(col0 + r) * K + k0 + scol];
    }
    __syncthreads();
#pragma unroll
    for (int kk = 0; kk < 2; ++kk) {
      bf16x8 af[4], bf[4];
#pragma unroll
      for (int m = 0; m < 4; ++m)
        af[m] = *(const bf16x8*)&lA[(wr * 64 + m * 16 + l15) * 72 + kk * 32 + g * 8];
#pragma unroll
      for (int n = 0; n < 4; ++n)
        bf[n] = *(const bf16x8*)&lB[(wc * 64 + n * 16 + l15) * 72 + kk * 32 + g * 8];
#pragma unroll
      for (int m = 0; m < 4; ++m)
#pragma unroll
        for (int n = 0; n < 4; ++n)
          acc[m][n] = __builtin_amdgcn_mfma_f32_16x16x32_bf16(af[m], bf[n], acc[m][n], 0, 0, 0);
    }
  }

#pragma unroll
  for (int m = 0; m < 4; ++m)
#pragma unroll
    for (int n = 0; n < 4; ++n) {
      const int r = row0 + wr * 64 + m * 16 + g * 4;
      const int c = col0 + wc * 64 + n * 16 + l15;
#pragma unroll
      for (int j = 0; j < 4; ++j) {
        if constexpr (std::is_same_v<OUT_T, u16>)
          C[(size_t)(r + j) * N + c] = f2bf(acc[m][n][j]);
        else
          C[(size_t)(r + j) * N + c] = acc[m][n][j];
      }
    }
}

// ---------------- fused attention ----------------
// grid: (Tq/128, B*H). block: 256 threads (4 waves).
// Phase 1: row stats (max, sum) over all K-tiles via online softmax (QK^T MFMA, stats only).
// Phase 2: recompute QK^T, write normalized attn (f32), P(bf16)->LDS, PV MFMA accumulate.
__global__ __launch_bounds__(256, 2)
void attn_fused(const u16* __restrict__ Qb, const u16* __restrict__ Kb,
                const u16* __restrict__ Vb, float* __restrict__ attn,
                u16* __restrict__ Ob) {
  __shared__ u16 lK[128 * 72];
  __shared__ u16 lVT[64 * 136];
  __shared__ u16 lP[128 * 136];
  __shared__ float lInv[128];
  __shared__ float lM[2][128];
  __shared__ float lL[2][128];

  const int tid  = threadIdx.x;
  const int lane = tid & 63;
  const int wid  = tid >> 6;
  const int wr = wid >> 1, wc = wid & 1;
  const int g = lane >> 4, l15 = lane & 15;
  const int bh = blockIdx.y;
  const int b  = bh >> 4;
  const int q0 = blockIdx.x * 128;
  const int srow = tid >> 3;
  const int scol = (tid & 7) * 8;
  const float scale = 0.125f;  // 1/sqrt(64)

  const size_t base = (size_t)b * TSEQ * DMODEL + (size_t)(bh & 15) * DHEAD;

  // Q fragments live in registers for the whole kernel.
  bf16x8 qf[4][2];
#pragma unroll
  for (int m = 0; m < 4; ++m)
#pragma unroll
    for (int kk = 0; kk < 2; ++kk)
      qf[m][kk] = *(const bf16x8*)&Qb[base + (size_t)(q0 + wr * 64 + m * 16 + l15) * DMODEL + kk * 32 + g * 8];

  float st_m[4][4], st_l[4][4];
#pragma unroll
  for (int m = 0; m < 4; ++m)
#pragma unroll
    for (int j = 0; j < 4; ++j) { st_m[m][j] = -1e30f; st_l[m][j] = 0.f; }

  const f32x4 vzero = {0.f, 0.f, 0.f, 0.f};

  // ---------------- phase 1: stats ----------------
  for (int t0 = 0; t0 < TSEQ; t0 += 128) {
    __syncthreads();
#pragma unroll
    for (int c = 0; c < 4; ++c) {
      int r = srow + c * 32;
      *(i32x4*)&lK[r * 72 + scol] = *(const i32x4*)&Kb[base + (size_t)(t0 + r) * DMODEL + scol];
    }
    __syncthreads();

    f32x4 s[4][4];
#pragma unroll
    for (int m = 0; m < 4; ++m)
#pragma unroll
      for (int n = 0; n < 4; ++n) s[m][n] = vzero;
#pragma unroll
    for (int kk = 0; kk < 2; ++kk) {
      bf16x8 kf[4];
#pragma unroll
      for (int n = 0; n < 4; ++n)
        kf[n] = *(const bf16x8*)&lK[(wc * 64 + n * 16 + l15) * 72 + kk * 32 + g * 8];
#pragma unroll
      for (int m = 0; m < 4; ++m)
#pragma unroll
        for (int n = 0; n < 4; ++n)
          s[m][n] = __builtin_amdgcn_mfma_f32_16x16x32_bf16(qf[m][kk], kf[n], s[m][n], 0, 0, 0);
    }

#pragma unroll
    for (int m = 0; m < 4; ++m)
#pragma unroll
      for (int j = 0; j < 4; ++j) {
        float vmax = fmaxf(fmaxf(s[m][0][j], s[m][1][j]), fmaxf(s[m][2][j], s[m][3][j])) * scale;
#pragma unroll
        for (int off = 1; off < 16; off <<= 1) vmax = fmaxf(vmax, __shfl_xor(vmax, off));
        float mo = st_m[m][j];
        float mn = fmaxf(mo, vmax);
        float sum = 0.f;
#pragma unroll
        for (int n = 0; n < 4; ++n) sum += __expf(s[m][n][j] * scale - mn);
#pragma unroll
        for (int off = 1; off < 16; off <<= 1) sum += __shfl_xor(sum, off);
        st_l[m][j] = st_l[m][j] * __expf(mo - mn) + sum;
        st_m[m][j] = mn;
      }
  }

  // ---- combine the two column-half partials (wc=0 / wc=1 saw interleaved halves) ----
  if (l15 == 0) {
#pragma unroll
    for (int m = 0; m < 4; ++m)
#pragma unroll
      for (int j = 0; j < 4; ++j) {
        int r = wr * 64 + m * 16 + g * 4 + j;
        lM[wc][r] = st_m[m][j];
        lL[wc][r] = st_l[m][j];
      }
  }
  __syncthreads();
#pragma unroll
  for (int m = 0; m < 4; ++m)
#pragma unroll
    for (int j = 0; j < 4; ++j) {
      int r = wr * 64 + m * 16 + g * 4 + j;
      float m0 = lM[0][r], m1 = lM[1][r];
      float l0 = lL[0][r], l1 = lL[1][r];
      float mf = fmaxf(m0, m1);
      float lf = l0 * __expf(m0 - mf) + l1 * __expf(m1 - mf);
      st_m[m][j] = mf;
      st_l[m][j] = 1.0f / lf;  // now holds 1/l
      if (wc == 0 && l15 == 0) lInv[r] = 1.0f / lf;
    }

  // ---------------- phase 2: recompute, write attn, PV ----------------
  f32x4 accO[2][4];
#pragma unroll
  for (int mi = 0; mi < 2; ++mi)
#pragma unroll
    for (int ni = 0; ni < 4; ++ni) accO[mi][ni] = vzero;

  for (int t0 = 0; t0 < TSEQ; t0 += 128) {
    __syncthreads();
#pragma unroll
    for (int c = 0; c < 4; ++c) {
      int r = srow + c * 32;
      *(i32x4*)&lK[r * 72 + scol] = *(const i32x4*)&Kb[base + (size_t)(t0 + r) * DMODEL + scol];
      bf16x8 v = *(const bf16x8*)&Vb[base + (size_t)(t0 + r) * DMODEL + scol];
#pragma unroll
      for (int i = 0; i < 8; ++i) lVT[(scol + i) * 136 + r] = (u16)v[i];
    }
    __syncthreads();

    f32x4 s[4][4];
#pragma unroll
    for (int m = 0; m < 4; ++m)
#pragma unroll
      for (int n = 0; n < 4; ++n) s[m][n] = vzero;
#pragma unroll
    for (int kk = 0; kk < 2; ++kk) {
      bf16x8 kf[4];
#pragma unroll
      for (int n = 0; n < 4; ++n)
        kf[n] = *(const bf16x8*)&lK[(wc * 64 + n * 16 + l15) * 72 + kk * 32 + g * 8];
#pragma unroll
      for (int m = 0; m < 4; ++m)
#pragma unroll
        for (int n = 0; n < 4; ++n)
          s[m][n] = __builtin_amdgcn_mfma_f32_16x16x32_bf16(qf[m][kk], kf[n], s[m][n], 0, 0, 0);
    }

#pragma unroll
    for (int m = 0; m < 4; ++m)
#pragma unroll
      for (int j = 0; j < 4; ++j) {
        float mj = st_m[m][j];
        float inv = st_l[m][j];
        int r = wr * 64 + m * 16 + g * 4 + j;
        size_t arow = ((size_t)bh * TSEQ + (q0 + r)) * TSEQ + t0 + wc * 64;
#pragma unroll
        for (int n = 0; n < 4; ++n) {
          float p = __expf(s[m][n][j] * scale - mj);   // unnormalized, <= 1
          attn[arow + n * 16 + l15] = p * inv;
          lP[r * 136 + wc * 64 + n * 16 + l15] = f2bf(p);
        }
      }
    __syncthreads();

    // PV: each wave owns 32 q-rows over the full 128-t tile, 64 d cols.
#pragma unroll
    for (int kk = 0; kk < 4; ++kk) {
      bf16x8 pf[2], vf[4];
#pragma unroll
      for (int mi = 0; mi < 2; ++mi)
        pf[mi] = *(const bf16x8*)&lP[(wid * 32 + mi * 16 + l15) * 136 + kk * 32 + g * 8];
#pragma unroll
      for (int ni = 0; ni < 4; ++ni)
        vf[ni] = *(const bf16x8*)&lVT[(ni * 16 + l15) * 136 + kk * 32 + g * 8];
#pragma unroll
      for (int mi = 0; mi < 2; ++mi)
#pragma unroll
        for (int ni = 0; ni < 4; ++ni)
          accO[mi][ni] = __builtin_amdgcn_mfma_f32_16x16x32_bf16(pf[mi], vf[ni], accO[mi][ni], 0, 0, 0);
    }
  }

  // epilogue: scale by 1/l, write O (bf16) in [B,T,C] layout (c = h*64+d)
#pragma unroll
  for (int mi = 0; mi < 2; ++mi)
#pragma unroll
    for (int ni = 0; ni < 4; ++ni)
#pragma unroll
      for (int j = 0; j < 4; ++j) {
        int rl = wid * 32 + mi * 16 + g * 4 + j;
        float inv = lInv[rl];
        Ob[base + (size_t)(q0 + rl) * DMODEL + ni * 16 + l15] = f2bf(accO[mi][ni][j] * inv);
      }
}

// ---------------- launch ----------------
extern "C" void kernel_launch(void* const* d_in, const int* in_sizes, int n_in,
                              void* d_out, int out_size, void* d_ws, size_t ws_size,
                              hipStream_t stream) {
  const float* x_q  = (const float*)d_in[0];
  const float* x_kv = (const float*)d_in[1];
  const float* w_q  = (const float*)d_in[2];
  const float* w_k  = (const float*)d_in[3];
  const float* w_v  = (const float*)d_in[4];
  const float* w_o  = (const float*)d_in[5];

  float* out  = (float*)d_out;
  float* attn = out + (size_t)2 * TSEQ * DMODEL;  // 4,194,304 floats

  const size_t X_E = (size_t)2 * TSEQ * DMODEL;   // 4M elems
  const size_t W_E = (size_t)DMODEL * DMODEL;     // 1M elems

  u16* ws     = (u16*)d_ws;
  u16* xq_bf  = ws;
  u16* xkv_bf = xq_bf + X_E;
  u16* wq_bf  = xkv_bf + X_E;
  u16* wk_bf  = wq_bf + W_E;
  u16* wv_bf  = wk_bf + W_E;
  u16* wo_bf  = wv_bf + W_E;
  u16* q_bf   = wo_bf + W_E;
  u16* k_bf   = q_bf + X_E;
  u16* v_bf   = k_bf + X_E;
  u16* o_bf   = v_bf + X_E;

  // f32 -> bf16
  {
    int n4 = (int)(X_E / 4);
    cvt_f32_bf16<<<dim3(n4 / 256), dim3(256), 0, stream>>>(x_q,  xq_bf,  n4);
    cvt_f32_bf16<<<dim3(n4 / 256), dim3(256), 0, stream>>>(x_kv, xkv_bf, n4);
    int n4w = (int)(W_E / 4);
    cvt_f32_bf16<<<dim3(n4w / 256), dim3(256), 0, stream>>>(w_q, wq_bf, n4w);
    cvt_f32_bf16<<<dim3(n4w / 256), dim3(256), 0, stream>>>(w_k, wk_bf, n4w);
    cvt_f32_bf16<<<dim3(n4w / 256), dim3(256), 0, stream>>>(w_v, wv_bf, n4w);
    cvt_f32_bf16<<<dim3(n4w / 256), dim3(256), 0, stream>>>(w_o, wo_bf, n4w);
  }

  // fused QKV projections: one launch, grid.z = 3 (768 blocks = 3/CU)
  {
    dim3 grid(DMODEL / 128, (2 * TSEQ) / 128, 3);
    gemm_bt<u16><<<grid, dim3(256), 0, stream>>>(
        xq_bf,  wq_bf, q_bf,
        xkv_bf, wk_bf, k_bf,
        xkv_bf, wv_bf, v_bf,
        2 * TSEQ, DMODEL, DMODEL);
  }

  // attention
  attn_fused<<<dim3(TSEQ / 128, 2 * NHEAD), dim3(256), 0, stream>>>(q_bf, k_bf, v_bf, attn, o_bf);

  // output projection -> f32
  {
    dim3 grid(DMODEL / 128, (2 * TSEQ) / 128, 1);
    gemm_bt<float><<<grid, dim3(256), 0, stream>>>(
        o_bf, wo_bf, out,
        o_bf, wo_bf, out,
        o_bf, wo_bf, out,
        2 * TSEQ, DMODEL, DMODEL);
  }
}

// Round 2
// 287.172 us; speedup vs baseline: 1.0502x; 1.0502x over previous
//
#include <hip/hip_runtime.h>
#include <stdint.h>
#include <type_traits>

typedef unsigned short u16;
typedef __attribute__((ext_vector_type(8))) short bf16x8;
typedef __attribute__((ext_vector_type(4))) float f32x4;

#define TSEQ   2048
#define DMODEL 1024
#define NHEAD  16
#define DHEAD  64
#define SCALE2 0.18033688011112042f   // (1/sqrt(64)) * log2(e)

__device__ __forceinline__ u16 f2bf(float f) {
  union { float f; uint32_t u; } v; v.f = f;
  uint32_t r = v.u + 0x7FFFu + ((v.u >> 16) & 1u);  // RNE
  return (u16)(r >> 16);
}

// async global->LDS, 16B per lane. dst must be wave-uniform; src is per-lane.
__device__ __forceinline__ void gload16(const u16* src, u16* dst) {
  __builtin_amdgcn_global_load_lds(
      (const __attribute__((address_space(1))) void*)src,
      (__attribute__((address_space(3))) void*)dst, 16, 0, 0);
}

// ---------------- fused f32 -> bf16 conversion (all 6 inputs, 1 launch) --------------
// dst layout: [xq 4M][xkv 4M][wq 1M][wk 1M][wv 1M][wo 1M] (u16 elements)
__global__ void cvt_all(const float* __restrict__ x_q, const float* __restrict__ x_kv,
                        const float* __restrict__ w_q, const float* __restrict__ w_k,
                        const float* __restrict__ w_v, const float* __restrict__ w_o,
                        u16* __restrict__ dst) {
  int i = blockIdx.x * blockDim.x + threadIdx.x;  // float4 index, < 3M
  const float4* src;
  if (i < (1 << 20)) {
    src = (const float4*)x_q + i;
  } else if (i < (2 << 20)) {
    src = (const float4*)x_kv + (i - (1 << 20));
  } else {
    int r = i - (2 << 20);
    int k = r >> 18;
    int off = r & ((1 << 18) - 1);
    const float* w = (k == 0) ? w_q : (k == 1) ? w_k : (k == 2) ? w_v : w_o;
    src = (const float4*)w + off;
  }
  float4 f = *src;
  ushort4 o;
  o.x = f2bf(f.x); o.y = f2bf(f.y); o.z = f2bf(f.z); o.w = f2bf(f.w);
  ((ushort4*)dst)[i] = o;
}

// ---------------- GEMM: C[M,N] = A[M,K] @ W[N,K]^T (m97-style gload_lds staging) -----
// 128x128 tile, BK=64, 4 waves (2x2). If TRANSZ2 and blockIdx.z==2, C is written
// transposed as vT[b*16+h][d][t] (bf16) for the attention PV B-operand.
template <typename OUT_T, bool TRANSZ2>
__global__ __launch_bounds__(256, 2)
void gemm_bt(const u16* A0, const u16* W0, void* C0,
             const u16* A1, const u16* W1, void* C1,
             const u16* A2, const u16* W2, void* C2,
             int M, int N, int K) {
  const u16* A = A0; const u16* W = W0; void* Cv = C0;
  if (blockIdx.z == 1) { A = A1; W = W1; Cv = C1; }
  if (blockIdx.z == 2) { A = A2; W = W2; Cv = C2; }

  __shared__ u16 lA[128 * 64];
  __shared__ u16 lB[128 * 64];

  const int tid  = threadIdx.x;
  const int lane = tid & 63;
  const int wid  = tid >> 6;
  const int wr = wid >> 1, wc = wid & 1;
  const int g = lane >> 4, l15 = lane & 15;
  const int row0 = blockIdx.y * 128;
  const int col0 = blockIdx.x * 128;
  const int lrow = lane >> 3;        // 0..7
  const int lcol = (lane & 7) * 8;   // 0..56 (16B chunks)

  const f32x4 vz = {0.f, 0.f, 0.f, 0.f};
  f32x4 acc[4][4];
#pragma unroll
  for (int m = 0; m < 4; ++m)
#pragma unroll
    for (int n = 0; n < 4; ++n) acc[m][n] = vz;

  for (int k0 = 0; k0 < K; k0 += 64) {
    __syncthreads();
#pragma unroll
    for (int i = 0; i < 4; ++i) {
      int r = wid * 32 + i * 8;
      gload16(&A[(size_t)(row0 + r + lrow) * K + k0 + lcol], &lA[r * 64]);
      gload16(&W[(size_t)(col0 + r + lrow) * K + k0 + lcol], &lB[r * 64]);
    }
    __syncthreads();
#pragma unroll
    for (int kk = 0; kk < 2; ++kk) {
      bf16x8 af[4], bfr[4];
#pragma unroll
      for (int m = 0; m < 4; ++m)
        af[m] = *(const bf16x8*)&lA[(wr * 64 + m * 16 + l15) * 64 + kk * 32 + g * 8];
#pragma unroll
      for (int n = 0; n < 4; ++n)
        bfr[n] = *(const bf16x8*)&lB[(wc * 64 + n * 16 + l15) * 64 + kk * 32 + g * 8];
#pragma unroll
      for (int m = 0; m < 4; ++m)
#pragma unroll
        for (int n = 0; n < 4; ++n)
          acc[m][n] = __builtin_amdgcn_mfma_f32_16x16x32_bf16(af[m], bfr[n], acc[m][n], 0, 0, 0);
    }
  }

  if (TRANSZ2 && blockIdx.z == 2) {
    // transposed write: vT[(b*NHEAD+h)*DHEAD + d][t]
    u16* C = (u16*)Cv;
#pragma unroll
    for (int m = 0; m < 4; ++m)
#pragma unroll
      for (int n = 0; n < 4; ++n) {
        const int c = col0 + wc * 64 + n * 16 + l15;     // channel = h*64+d
        const size_t rowbase = ((size_t)((c >> 6)) * DHEAD + (c & 63)) * TSEQ;
#pragma unroll
        for (int j = 0; j < 4; ++j) {
          const int r = row0 + wr * 64 + m * 16 + g * 4 + j;  // token
          const int b = r >> 11, t = r & 2047;
          C[(size_t)b * NHEAD * DHEAD * TSEQ + rowbase + t] = f2bf(acc[m][n][j]);
        }
      }
  } else {
    OUT_T* C = (OUT_T*)Cv;
#pragma unroll
    for (int m = 0; m < 4; ++m)
#pragma unroll
      for (int n = 0; n < 4; ++n) {
        const int r = row0 + wr * 64 + m * 16 + g * 4;
        const int c = col0 + wc * 64 + n * 16 + l15;
#pragma unroll
        for (int j = 0; j < 4; ++j) {
          if constexpr (std::is_same_v<OUT_T, u16>)
            C[(size_t)(r + j) * N + c] = f2bf(acc[m][n][j]);
          else
            C[(size_t)(r + j) * N + c] = acc[m][n][j];
        }
      }
  }
}

// ---------------- fused attention, S^T orientation, fixed max=0 ----------------
// grid: (Tq/128, B*H), 256 threads (4 waves: wq=wid&1 q-half, wt=wid>>1 t-half).
// Phase 1: S^T = K·Q^T per 128-t tile; accumulate per-lane sum of exp2 (no max).
// Phase 2: recompute S^T, write normalized attn (f32x4, line-coalesced), pack P
//          bf16 to LDS (b64 writes), PV MFMA with V^T staged linear via gload_lds.
__global__ __launch_bounds__(256, 2)
void attn_fused(const u16* __restrict__ Qb, const u16* __restrict__ Kb,
                const u16* __restrict__ VTb, float* __restrict__ attn,
                u16* __restrict__ Ob) {
  __shared__ u16 lK[128 * 64];     // K tile  [t:128][d:64]
  __shared__ u16 lVT[64 * 128];    // V^T tile [d:64][t:128]
  __shared__ u16 lP[128 * 136];    // P tile  [q:128][t:128+pad]
  __shared__ float lL[2][128];
  __shared__ float lInv[128];

  const int tid  = threadIdx.x;
  const int lane = tid & 63;
  const int wid  = tid >> 6;
  const int wq = wid & 1, wt = wid >> 1;
  const int g = lane >> 4, l15 = lane & 15;
  const int bh = blockIdx.y;
  const int b  = bh >> 4;
  const int q0 = blockIdx.x * 128;
  const int lrow = lane >> 3;
  const int lcol = (lane & 7) * 8;

  const size_t xbase  = (size_t)b * TSEQ * DMODEL + (size_t)(bh & 15) * DHEAD;
  const size_t vtbase = (size_t)bh * DHEAD * TSEQ;

  // Q fragments in registers (b-operand: rows q = wq*64+n*16+l15)
  bf16x8 qf[4][2];
#pragma unroll
  for (int n = 0; n < 4; ++n)
#pragma unroll
    for (int kk = 0; kk < 2; ++kk)
      qf[n][kk] = *(const bf16x8*)&Qb[xbase + (size_t)(q0 + wq * 64 + n * 16 + l15) * DMODEL + kk * 32 + g * 8];

  const f32x4 vz = {0.f, 0.f, 0.f, 0.f};
  float psum[4] = {0.f, 0.f, 0.f, 0.f};

  // ---------------- phase 1: exp-sums ----------------
  for (int t0 = 0; t0 < TSEQ; t0 += 128) {
    __syncthreads();
#pragma unroll
    for (int i = 0; i < 4; ++i) {
      int r = wid * 32 + i * 8;
      gload16(&Kb[xbase + (size_t)(t0 + r + lrow) * DMODEL + lcol], &lK[r * 64]);
    }
    __syncthreads();

    f32x4 s[4][4];
#pragma unroll
    for (int m = 0; m < 4; ++m)
#pragma unroll
      for (int n = 0; n < 4; ++n) s[m][n] = vz;
#pragma unroll
    for (int kk = 0; kk < 2; ++kk) {
      bf16x8 kf[4];
#pragma unroll
      for (int m = 0; m < 4; ++m)
        kf[m] = *(const bf16x8*)&lK[(wt * 64 + m * 16 + l15) * 64 + kk * 32 + g * 8];
#pragma unroll
      for (int m = 0; m < 4; ++m)
#pragma unroll
        for (int n = 0; n < 4; ++n)
          s[m][n] = __builtin_amdgcn_mfma_f32_16x16x32_bf16(kf[m], qf[n][kk], s[m][n], 0, 0, 0);
    }
#pragma unroll
    for (int m = 0; m < 4; ++m)
#pragma unroll
      for (int n = 0; n < 4; ++n)
#pragma unroll
        for (int j = 0; j < 4; ++j)
          psum[n] += __builtin_amdgcn_exp2f(s[m][n][j] * SCALE2);
  }

  // reduce over g (lanes sharing q differ only in bits 4..5)
#pragma unroll
  for (int n = 0; n < 4; ++n) {
    psum[n] += __shfl_xor(psum[n], 16);
    psum[n] += __shfl_xor(psum[n], 32);
  }
  if (lane < 16) {
#pragma unroll
    for (int n = 0; n < 4; ++n) lL[wt][wq * 64 + n * 16 + lane] = psum[n];
  }
  __syncthreads();
  if (tid < 128) lInv[tid] = 1.0f / (lL[0][tid] + lL[1][tid]);
  __syncthreads();
  float inv_n[4];
#pragma unroll
  for (int n = 0; n < 4; ++n) inv_n[n] = lInv[wq * 64 + n * 16 + l15];

  // ---------------- phase 2: recompute, write attn, PV ----------------
  f32x4 accO[2][4];
#pragma unroll
  for (int mi = 0; mi < 2; ++mi)
#pragma unroll
    for (int ni = 0; ni < 4; ++ni) accO[mi][ni] = vz;

  for (int t0 = 0; t0 < TSEQ; t0 += 128) {
    __syncthreads();
#pragma unroll
    for (int i = 0; i < 4; ++i) {
      int r = wid * 32 + i * 8;
      gload16(&Kb[xbase + (size_t)(t0 + r + lrow) * DMODEL + lcol], &lK[r * 64]);
      int rv = wid * 16 + i * 4;
      gload16(&VTb[vtbase + (size_t)(rv + (lane >> 4)) * TSEQ + t0 + (lane & 15) * 8], &lVT[rv * 128]);
    }
    __syncthreads();

    f32x4 s[4][4];
#pragma unroll
    for (int m = 0; m < 4; ++m)
#pragma unroll
      for (int n = 0; n < 4; ++n) s[m][n] = vz;
#pragma unroll
    for (int kk = 0; kk < 2; ++kk) {
      bf16x8 kf[4];
#pragma unroll
      for (int m = 0; m < 4; ++m)
        kf[m] = *(const bf16x8*)&lK[(wt * 64 + m * 16 + l15) * 64 + kk * 32 + g * 8];
#pragma unroll
      for (int m = 0; m < 4; ++m)
#pragma unroll
        for (int n = 0; n < 4; ++n)
          s[m][n] = __builtin_amdgcn_mfma_f32_16x16x32_bf16(kf[m], qf[n][kk], s[m][n], 0, 0, 0);
    }

#pragma unroll
    for (int m = 0; m < 4; ++m)
#pragma unroll
      for (int n = 0; n < 4; ++n) {
        const int q  = wq * 64 + n * 16 + l15;
        const int tt = wt * 64 + m * 16 + g * 4;
        f32x4 pv;
        u16 pb[4];
#pragma unroll
        for (int j = 0; j < 4; ++j) {
          float p = __builtin_amdgcn_exp2f(s[m][n][j] * SCALE2);
          pv[j] = p * inv_n[n];
          pb[j] = f2bf(p);
        }
        *(f32x4*)&attn[((size_t)bh * TSEQ + q0 + q) * TSEQ + t0 + tt] = pv;
        uint64_t pk = (uint64_t)pb[0] | ((uint64_t)pb[1] << 16) |
                      ((uint64_t)pb[2] << 32) | ((uint64_t)pb[3] << 48);
        *(uint64_t*)&lP[q * 136 + tt] = pk;
      }
    __syncthreads();

    // PV: wave owns 32 q rows x 64 d cols, k over the 128-t tile
#pragma unroll
    for (int kt = 0; kt < 4; ++kt) {
      bf16x8 pf[2], vf[4];
#pragma unroll
      for (int mi = 0; mi < 2; ++mi)
        pf[mi] = *(const bf16x8*)&lP[(wid * 32 + mi * 16 + l15) * 136 + kt * 32 + g * 8];
#pragma unroll
      for (int ni = 0; ni < 4; ++ni)
        vf[ni] = *(const bf16x8*)&lVT[(ni * 16 + l15) * 128 + kt * 32 + g * 8];
#pragma unroll
      for (int mi = 0; mi < 2; ++mi)
#pragma unroll
        for (int ni = 0; ni < 4; ++ni)
          accO[mi][ni] = __builtin_amdgcn_mfma_f32_16x16x32_bf16(pf[mi], vf[ni], accO[mi][ni], 0, 0, 0);
    }
  }

  // epilogue: normalize, write O bf16 in [B,T,C]
#pragma unroll
  for (int mi = 0; mi < 2; ++mi)
#pragma unroll
    for (int ni = 0; ni < 4; ++ni)
#pragma unroll
      for (int j = 0; j < 4; ++j) {
        int q = wid * 32 + mi * 16 + g * 4 + j;
        Ob[xbase + (size_t)(q0 + q) * DMODEL + ni * 16 + l15] = f2bf(accO[mi][ni][j] * lInv[q]);
      }
}

// ---------------- launch ----------------
extern "C" void kernel_launch(void* const* d_in, const int* in_sizes, int n_in,
                              void* d_out, int out_size, void* d_ws, size_t ws_size,
                              hipStream_t stream) {
  const float* x_q  = (const float*)d_in[0];
  const float* x_kv = (const float*)d_in[1];
  const float* w_q  = (const float*)d_in[2];
  const float* w_k  = (const float*)d_in[3];
  const float* w_v  = (const float*)d_in[4];
  const float* w_o  = (const float*)d_in[5];

  float* out  = (float*)d_out;
  float* attn = out + (size_t)2 * TSEQ * DMODEL;

  const size_t X_E = (size_t)2 * TSEQ * DMODEL;  // 4M
  const size_t W_E = (size_t)DMODEL * DMODEL;    // 1M

  u16* ws     = (u16*)d_ws;
  u16* xq_bf  = ws;                 // 4M
  u16* xkv_bf = xq_bf + X_E;        // 4M
  u16* wq_bf  = xkv_bf + X_E;       // 1M
  u16* wk_bf  = wq_bf + W_E;
  u16* wv_bf  = wk_bf + W_E;
  u16* wo_bf  = wv_bf + W_E;
  u16* q_bf   = wo_bf + W_E;        // 4M
  u16* k_bf   = q_bf + X_E;         // 4M
  u16* vt_bf  = k_bf + X_E;         // 4M  (transposed [BH][D][T])
  u16* o_bf   = vt_bf + X_E;        // 4M

  // all f32->bf16 conversions, one launch (3M float4)
  cvt_all<<<dim3(3 * 1024 * 1024 / 256), dim3(256), 0, stream>>>(
      x_q, x_kv, w_q, w_k, w_v, w_o, ws);

  // fused QKV projections (z=2 writes V transposed)
  {
    dim3 grid(DMODEL / 128, (2 * TSEQ) / 128, 3);
    gemm_bt<u16, true><<<grid, dim3(256), 0, stream>>>(
        xq_bf,  wq_bf, q_bf,
        xkv_bf, wk_bf, k_bf,
        xkv_bf, wv_bf, vt_bf,
        2 * TSEQ, DMODEL, DMODEL);
  }

  // attention
  attn_fused<<<dim3(TSEQ / 128, 2 * NHEAD), dim3(256), 0, stream>>>(
      q_bf, k_bf, vt_bf, attn, o_bf);

  // output projection -> f32
  {
    dim3 grid(DMODEL / 128, (2 * TSEQ) / 128, 1);
    gemm_bt<float, false><<<grid, dim3(256), 0, stream>>>(
        o_bf, wo_bf, out,
        o_bf, wo_bf, out,
        o_bf, wo_bf, out,
        2 * TSEQ, DMODEL, DMODEL);
  }
}